// Round 5
// baseline (515.911 us; speedup 1.0000x reference)
//
#include <hip/hip_runtime.h>
#include <stdint.h>

// ReLU relaxation (alpha-CROWN style), N = 8192.
// Output (f32), flat: [conc_low (n)] [conc_up (n)] [A_low (n+1)^2] [A_up (n+1)^2]
// A_low/A_up are diagonal + (A_up) last row; everything else zero.
//
// Timing model (r0-r4): harness poison fill (2.148 GB @ 6.2 TB/s = 345 us) is
// inside the timed region and fixed. Controllable = one 537 MB output write:
//   R0 memset+scatter 173 | R1 NT/loop 212 | R2 cached/blocked 243
//   R3 cached/loop 186    | R4 cached/flat 163  (best)
// Two models fit: (A) user stores stuck at ~3.3-4 TB/s vs fill's 6.2 — MLP
// per thread is the last untested structural difference vs fillBufferAligned;
// (B) kernel already ~6 TB/s + ~75 us fixed harness overhead. This round
// tests the discriminating cell: flat one-shot threads x 4 independent
// grid-strided dwordx4 stores each (fill-kernel mimic), fully unrolled.

typedef float f32x4 __attribute__((ext_vector_type(4)));

struct NodeVals { float diag_low, diag_up, bias_up, conc_low, conc_up; };

__device__ __forceinline__ NodeVals node_vals(float l, float u, float a_raw) {
    NodeVals nv;
    float a = fminf(fmaxf(a_raw, 0.f), 1.f);
    bool active   = (u > 0.f) && (l >= 0.f);
    bool unstable = (u > 0.f) && (l < 0.f);
    float denom = u - l;
    float lam = u / ((denom == 0.f) ? 1.f : denom);
    nv.diag_low = active ? 1.f : (unstable ? a : 0.f);
    nv.diag_up  = active ? 1.f : (unstable ? lam : 0.f);
    nv.bias_up  = unstable ? (-lam * l) : 0.f;
    nv.conc_low = active ? l : (unstable ? (a * l) : 0.f);
    nv.conc_up  = (u > 0.f) ? u : 0.f;
    return nv;
}

template <uint32_t NP1>
__device__ __forceinline__ void process_chunk(uint32_t j,
        const float* __restrict__ lower,
        const float* __restrict__ upper,
        const float* __restrict__ alphas,
        f32x4* __restrict__ out4) {
    constexpr uint32_t N    = NP1 - 1;
    constexpr uint32_t NPSQ = NP1 * NP1;       // 67,125,249 < 2^27
    constexpr uint32_t CONC = 2 * N;           // 16384

    const uint32_t e0 = j * 4u;
    f32x4 v = (f32x4){0.f, 0.f, 0.f, 0.f};

    if (e0 < CONC) {
        // Dense concrete-bounds region (N % 4 == 0: no straddles).
        if (e0 < N) {
            const f32x4 l4 = *(const f32x4*)(lower  + e0);
            const f32x4 u4 = *(const f32x4*)(upper  + e0);
            const f32x4 a4 = *(const f32x4*)(alphas + e0);
            #pragma unroll
            for (int k = 0; k < 4; ++k)
                v[k] = node_vals(l4[k], u4[k], a4[k]).conc_low;
        } else {
            const f32x4 u4 = *(const f32x4*)(upper + (e0 - N));
            #pragma unroll
            for (int k = 0; k < 4; ++k)
                v[k] = (u4[k] > 0.f) ? u4[k] : 0.f;
        }
    } else {
        // A_low / A_up region. One magic-div (const divisor) per chunk.
        const uint32_t g   = e0 - CONC;
        const uint32_t mat = (g >= NPSQ) ? 1u : 0u;   // 0 = A_low, 1 = A_up
        const uint32_t h   = mat ? (g - NPSQ) : g;
        const uint32_t r   = h / NP1;
        const uint32_t c   = h - r * NP1;

        // Slow iff the chunk can contain a nonzero: holds this row's diagonal,
        // wraps a row boundary (next-row diag / matrix boundary), or lies in
        // A_up's last (bias) row.
        const bool slow = ((r - c) <= 3u) |
                          (c > (uint32_t)(NP1 - 4)) |
                          ((mat != 0u) & (r == N));
        if (slow) {
            #pragma unroll
            for (int k = 0; k < 4; ++k) {
                const uint32_t gk = g + (uint32_t)k;
                const uint32_t mk = (gk >= NPSQ) ? 1u : 0u;
                const uint32_t hk = mk ? (gk - NPSQ) : gk;
                const uint32_t rk = hk / NP1;
                const uint32_t ck = hk - rk * NP1;
                float val = 0.f;
                if (rk == ck) {
                    if (rk == N) {
                        val = 1.f;                        // A_*[n,n]
                    } else {
                        NodeVals nv = node_vals(lower[rk], upper[rk], alphas[rk]);
                        val = mk ? nv.diag_up : nv.diag_low;
                    }
                } else if (mk && rk == N) {               // A_up bias row
                    NodeVals nv = node_vals(lower[ck], upper[ck], alphas[ck]);
                    val = nv.bias_up;
                }
                v[k] = val;
            }
        }
    }
    out4[j] = v;   // plain cached dwordx4 store, 1 KB contiguous per wave
}

template <uint32_t NP1>
__global__ __launch_bounds__(256) void fused_fill_flat4(
        const float* __restrict__ lower,
        const float* __restrict__ upper,
        const float* __restrict__ alphas,
        float* __restrict__ out) {
    constexpr uint32_t N    = NP1 - 1;
    constexpr uint32_t NPSQ = NP1 * NP1;
    constexpr uint32_t CONC = 2 * N;
    constexpr uint32_t T    = CONC + 2 * NPSQ;   // 134,266,882
    constexpr uint32_t C4   = T / 4;             // 33,566,720 16B chunks
    constexpr uint32_t STRD = C4 / 4;            // 8,391,680 (grid-stride)
    static_assert(N % 4 == 0 && T % 4 == 2, "layout assumptions");
    static_assert(C4 % 4u == 0 && STRD % 256u == 0, "exact cover");

    const uint32_t t = blockIdx.x * 256u + threadIdx.x;
    f32x4* __restrict__ out4 = (f32x4*)out;

    // 4 independent grid-strided stores per one-shot thread (fill mimic).
    process_chunk<NP1>(t,            lower, upper, alphas, out4);
    process_chunk<NP1>(t + STRD,     lower, upper, alphas, out4);
    process_chunk<NP1>(t + 2 * STRD, lower, upper, alphas, out4);
    process_chunk<NP1>(t + 3 * STRD, lower, upper, alphas, out4);

    // Tail: last 2 elements = A_up[n, n-1] (bias) and A_up[n, n] (= 1).
    if (t == 0) {
        NodeVals nv = node_vals(lower[N - 1], upper[N - 1], alphas[N - 1]);
        out[(size_t)T - 2] = nv.bias_up;
        out[(size_t)T - 1] = 1.f;
    }
}

// Correctness fallback for any n (never taken in the bench; scalar, runtime div).
__global__ void generic_fill(const float* __restrict__ lower,
                             const float* __restrict__ upper,
                             const float* __restrict__ alphas,
                             float* __restrict__ out, int n) {
    const uint32_t np1  = (uint32_t)n + 1;
    const size_t   npsq = (size_t)np1 * np1;
    const size_t   conc = 2 * (size_t)n;
    const size_t   T    = conc + 2 * npsq;
    const size_t stride = (size_t)gridDim.x * blockDim.x;
    for (size_t e = (size_t)blockIdx.x * blockDim.x + threadIdx.x; e < T; e += stride) {
        float val = 0.f;
        if (e < (size_t)n) {
            val = node_vals(lower[e], upper[e], alphas[e]).conc_low;
        } else if (e < conc) {
            size_t i = e - n;
            val = node_vals(lower[i], upper[i], alphas[i]).conc_up;
        } else {
            size_t g = e - conc;
            int mat = (g >= npsq) ? 1 : 0;
            size_t h = mat ? (g - npsq) : g;
            uint32_t r = (uint32_t)(h / np1);
            uint32_t c = (uint32_t)(h - (size_t)r * np1);
            if (r == c) {
                if (r == (uint32_t)n) val = 1.f;
                else {
                    NodeVals nv = node_vals(lower[r], upper[r], alphas[r]);
                    val = mat ? nv.diag_up : nv.diag_low;
                }
            } else if (mat && r == (uint32_t)n) {
                val = node_vals(lower[c], upper[c], alphas[c]).bias_up;
            }
        }
        out[e] = val;
    }
}

extern "C" void kernel_launch(void* const* d_in, const int* in_sizes, int n_in,
                              void* d_out, int out_size, void* d_ws, size_t ws_size,
                              hipStream_t stream) {
    const float* lower  = (const float*)d_in[0];
    const float* upper  = (const float*)d_in[1];
    const float* alphas = (const float*)d_in[2];
    float* out = (float*)d_out;
    const int n = in_sizes[0];

    if (n == 8192) {
        // 33,566,720 chunks / 4 per thread = 8,391,680 threads
        // = 32,780 blocks x 256. One-shot threads, 4 stores each.
        fused_fill_flat4<8193><<<32780, 256, 0, stream>>>(lower, upper, alphas, out);
    } else {
        generic_fill<<<2048, 256, 0, stream>>>(lower, upper, alphas, out, n);
    }
}

// Round 6
// 508.145 us; speedup vs baseline: 1.0153x; 1.0153x over previous
//
#include <hip/hip_runtime.h>
#include <stdint.h>

// ReLU relaxation (alpha-CROWN style), N = 8192.
// Output (f32), flat: [conc_low (n)] [conc_up (n)] [A_low (n+1)^2] [A_up (n+1)^2]
// A_low/A_up are diagonal + (A_up) last row; everything else zero.
//
// FINAL (revert to R4, the measured best = 508.0 us).
// Timing decomposition (r0-r5, cross-validated over two independent bulk-write
// structures):
//   345 us  harness poison fill (in timed region; immovable)
//   ~82 us  one 537 MB output write at the device write ceiling (~6.5 TB/s)
//   ~80 us  fixed harness overhead (identical residual in R0 driver-fill path
//           and R4 fused path -> not kernel-attributable)
// Lever audit: NT stores (R1: worse), thread-blocked stores (R2: worse),
// persistent loop (R3: worse), 4 stores/thread MLP (R5: worse). Flat one-shot
// grid + cached lane-contiguous dwordx4 stores is the roofline configuration.

typedef float f32x4 __attribute__((ext_vector_type(4)));

struct NodeVals { float diag_low, diag_up, bias_up, conc_low, conc_up; };

__device__ __forceinline__ NodeVals node_vals(float l, float u, float a_raw) {
    NodeVals nv;
    float a = fminf(fmaxf(a_raw, 0.f), 1.f);
    bool active   = (u > 0.f) && (l >= 0.f);
    bool unstable = (u > 0.f) && (l < 0.f);
    float denom = u - l;
    float lam = u / ((denom == 0.f) ? 1.f : denom);
    nv.diag_low = active ? 1.f : (unstable ? a : 0.f);
    nv.diag_up  = active ? 1.f : (unstable ? lam : 0.f);
    nv.bias_up  = unstable ? (-lam * l) : 0.f;
    nv.conc_low = active ? l : (unstable ? (a * l) : 0.f);
    nv.conc_up  = (u > 0.f) ? u : 0.f;
    return nv;
}

template <uint32_t NP1>
__global__ __launch_bounds__(256) void fused_fill_flat(
        const float* __restrict__ lower,
        const float* __restrict__ upper,
        const float* __restrict__ alphas,
        float* __restrict__ out) {
    constexpr uint32_t N    = NP1 - 1;
    constexpr uint32_t NPSQ = NP1 * NP1;        // 67,125,249 < 2^27
    constexpr uint32_t CONC = 2 * N;            // 16384
    constexpr uint32_t T    = CONC + 2 * NPSQ;  // 134,266,882
    static_assert(N % 4 == 0 && T % 4 == 2, "layout assumptions");

    const uint32_t j  = blockIdx.x * 256u + threadIdx.x;  // 16B chunk index
    const uint32_t e0 = j * 4u;
    f32x4* __restrict__ out4 = (f32x4*)out;
    f32x4 v = (f32x4){0.f, 0.f, 0.f, 0.f};

    if (e0 < CONC) {
        // Dense concrete-bounds region (N % 4 == 0: no straddles).
        if (e0 < N) {
            const f32x4 l4 = *(const f32x4*)(lower  + e0);
            const f32x4 u4 = *(const f32x4*)(upper  + e0);
            const f32x4 a4 = *(const f32x4*)(alphas + e0);
            #pragma unroll
            for (int k = 0; k < 4; ++k)
                v[k] = node_vals(l4[k], u4[k], a4[k]).conc_low;
        } else {
            const f32x4 u4 = *(const f32x4*)(upper + (e0 - N));
            #pragma unroll
            for (int k = 0; k < 4; ++k)
                v[k] = (u4[k] > 0.f) ? u4[k] : 0.f;
        }
    } else {
        // A_low / A_up region. One magic-div (const divisor) per chunk.
        const uint32_t g   = e0 - CONC;
        const uint32_t mat = (g >= NPSQ) ? 1u : 0u;   // 0 = A_low, 1 = A_up
        const uint32_t h   = mat ? (g - NPSQ) : g;
        const uint32_t r   = h / NP1;
        const uint32_t c   = h - r * NP1;

        // Slow iff the chunk can contain a nonzero: holds this row's diagonal,
        // wraps a row boundary (next-row diag / matrix boundary), or lies in
        // A_up's last (bias) row.
        const bool slow = ((r - c) <= 3u) |
                          (c > (uint32_t)(NP1 - 4)) |
                          ((mat != 0u) & (r == N));
        if (slow) {
            #pragma unroll
            for (int k = 0; k < 4; ++k) {
                const uint32_t gk = g + (uint32_t)k;
                const uint32_t mk = (gk >= NPSQ) ? 1u : 0u;
                const uint32_t hk = mk ? (gk - NPSQ) : gk;
                const uint32_t rk = hk / NP1;
                const uint32_t ck = hk - rk * NP1;
                float val = 0.f;
                if (rk == ck) {
                    if (rk == N) {
                        val = 1.f;                        // A_*[n,n]
                    } else {
                        NodeVals nv = node_vals(lower[rk], upper[rk], alphas[rk]);
                        val = mk ? nv.diag_up : nv.diag_low;
                    }
                } else if (mk && rk == N) {               // A_up bias row
                    NodeVals nv = node_vals(lower[ck], upper[ck], alphas[ck]);
                    val = nv.bias_up;
                }
                v[k] = val;
            }
        }
    }

    out4[j] = v;   // plain cached dwordx4 store, 1 KB contiguous per wave

    // Tail: last 2 elements = A_up[n, n-1] (bias) and A_up[n, n] (= 1).
    if (j == 0) {
        NodeVals nv = node_vals(lower[N - 1], upper[N - 1], alphas[N - 1]);
        out[(size_t)T - 2] = nv.bias_up;
        out[(size_t)T - 1] = 1.f;
    }
}

// Correctness fallback for any n (never taken in the bench; scalar, runtime div).
__global__ void generic_fill(const float* __restrict__ lower,
                             const float* __restrict__ upper,
                             const float* __restrict__ alphas,
                             float* __restrict__ out, int n) {
    const uint32_t np1  = (uint32_t)n + 1;
    const size_t   npsq = (size_t)np1 * np1;
    const size_t   conc = 2 * (size_t)n;
    const size_t   T    = conc + 2 * npsq;
    const size_t stride = (size_t)gridDim.x * blockDim.x;
    for (size_t e = (size_t)blockIdx.x * blockDim.x + threadIdx.x; e < T; e += stride) {
        float val = 0.f;
        if (e < (size_t)n) {
            val = node_vals(lower[e], upper[e], alphas[e]).conc_low;
        } else if (e < conc) {
            size_t i = e - n;
            val = node_vals(lower[i], upper[i], alphas[i]).conc_up;
        } else {
            size_t g = e - conc;
            int mat = (g >= npsq) ? 1 : 0;
            size_t h = mat ? (g - npsq) : g;
            uint32_t r = (uint32_t)(h / np1);
            uint32_t c = (uint32_t)(h - (size_t)r * np1);
            if (r == c) {
                if (r == (uint32_t)n) val = 1.f;
                else {
                    NodeVals nv = node_vals(lower[r], upper[r], alphas[r]);
                    val = mat ? nv.diag_up : nv.diag_low;
                }
            } else if (mat && r == (uint32_t)n) {
                val = node_vals(lower[c], upper[c], alphas[c]).bias_up;
            }
        }
        out[e] = val;
    }
}

extern "C" void kernel_launch(void* const* d_in, const int* in_sizes, int n_in,
                              void* d_out, int out_size, void* d_ws, size_t ws_size,
                              hipStream_t stream) {
    const float* lower  = (const float*)d_in[0];
    const float* upper  = (const float*)d_in[1];
    const float* alphas = (const float*)d_in[2];
    float* out = (float*)d_out;
    const int n = in_sizes[0];

    if (n == 8192) {
        // Flat one-shot grid, fill-kernel style: C4 = 33,566,720 chunks
        // = 131,120 blocks x 256 threads exactly (no bounds check).
        constexpr uint32_t C4 = (2u * 8192u + 2u * 8193u * 8193u) / 4u;
        static_assert(C4 % 256u == 0, "exact cover");
        fused_fill_flat<8193><<<C4 / 256u, 256, 0, stream>>>(lower, upper, alphas, out);
    } else {
        generic_fill<<<2048, 256, 0, stream>>>(lower, upper, alphas, out, n);
    }
}